// Round 22
// baseline (148.472 us; speedup 1.0000x reference)
//
#include <hip/hip_runtime.h>
#include <hip/hip_bf16.h>
#include <hip/hip_cooperative_groups.h>

namespace cg = cooperative_groups;

// Problem constants
#define BB 128        // batch
#define NN 100000     // memory bank size
#define DD 256        // feat dim (K)
#define CC 2000       // num classes
#define SS 751        // source classes
#define INVTEMP 20.0f // 1/0.05
#define EPSV 1e-6f

#define NTILES_MAX 3563    // 2000 + 100000/64 upper bound on padded tiles
#define COOP_BLOCKS 256
#define COOP_THREADS 65536 // 256*256

typedef __attribute__((ext_vector_type(8))) short bf16x8;
typedef __attribute__((ext_vector_type(8))) unsigned short u16x8;
typedef __attribute__((ext_vector_type(4))) float f32x4;

__device__ __forceinline__ unsigned short f2bf(float x) {
    unsigned int u = __float_as_uint(x);
    u += 0x7fffu + ((u >> 16) & 1u);   // round-to-nearest-even
    return (unsigned short)(u >> 16);
}

// 8x f32 -> 8x bf16 (16B) via HW packed converts (RNE)
__device__ __forceinline__ u16x8 cvt8u(float4 a, float4 b) {
    union { unsigned u[4]; u16x8 v; } cv;
    asm("v_cvt_pk_bf16_f32 %0, %1, %2" : "=v"(cv.u[0]) : "v"(a.x), "v"(a.y));
    asm("v_cvt_pk_bf16_f32 %0, %1, %2" : "=v"(cv.u[1]) : "v"(a.z), "v"(a.w));
    asm("v_cvt_pk_bf16_f32 %0, %1, %2" : "=v"(cv.u[2]) : "v"(b.x), "v"(b.y));
    asm("v_cvt_pk_bf16_f32 %0, %1, %2" : "=v"(cv.u[3]) : "v"(b.z), "v"(b.w));
    return cv.v;
}

// ---------------- cooperative prep: inb-prep + hist -> scan -> scatter ----------------
// One launch replaces 3 kernels (saves 2 dispatch gaps + ramps).
// Phase A (grid-stride): i<8192 -> build inb chunk i; else histogram element i-8192.
// grid.sync. Phase B: block 0 runs the padded-tile scan (64-row tiles).
// grid.sync. Phase C (grid-stride): scatter class-sorted indexes.
// inb: 16B chunk ch = (nr*8+kc)*64+l holds row nr*16+(l&15) (0..127 inputs,
// 128..255 inputs2), k = kc*32+(l>>4)*8+j.  tile_meta[t] = (c<<5)|local_j.
__global__ __launch_bounds__(256) void prep_coop(
    const int* __restrict__ labels, int* __restrict__ counts,
    const float* __restrict__ in1, const float* __restrict__ in2,
    unsigned short* __restrict__ inb,
    int* __restrict__ tile_start, int* __restrict__ cursor,
    int* __restrict__ tile_meta, int* __restrict__ ntiles_total,
    float* __restrict__ out, int* __restrict__ sorted_idx)
{
    cg::grid_group grid = cg::this_grid();
    const int gtid = blockIdx.x * 256 + threadIdx.x;

    // ---- Phase A: inb prep + histogram ----
    for (int i = gtid; i < 8192 + NN; i += COOP_THREADS) {
        if (i < 8192) {
            int l  = i & 63;
            int kc = (i >> 6) & 7;
            int nr = i >> 9;
            int row = nr * 16 + (l & 15);
            const float* src = (row < BB) ? (in1 + (size_t)row * DD)
                                          : (in2 + (size_t)(row - BB) * DD);
            int k0 = kc * 32 + ((l >> 4) << 3);
            u16x8 o;
            #pragma unroll
            for (int j = 0; j < 8; ++j) o[j] = f2bf(src[k0 + j]);
            *(u16x8*)(inb + (size_t)i * 8) = o;
        } else {
            int n = i - 8192;
            atomicAdd(&counts[labels[n]], 1);
        }
    }
    grid.sync();

    // ---- Phase B: scan (block 0 only) ----
    if (blockIdx.x == 0) {
        const int PT = 8;
        int tid = threadIdx.x;
        if (tid == 0) { out[0] = 0.f; out[1] = 0.f; }
        int tcnt[PT];
        int tot = 0;
        #pragma unroll
        for (int i = 0; i < PT; ++i) {
            int c = tid * PT + i;
            tcnt[i] = (c < CC) ? ((counts[c] + 63) >> 6) : 0;
            tot += tcnt[i];
        }
        __shared__ int sh[256];
        sh[tid] = tot;
        __syncthreads();
        for (int ofs = 1; ofs < 256; ofs <<= 1) {
            int v = (tid >= ofs) ? sh[tid - ofs] : 0;
            __syncthreads();
            sh[tid] += v;
            __syncthreads();
        }
        if (tid == 255) *ntiles_total = sh[255];
        int run = sh[tid] - tot;
        #pragma unroll
        for (int i = 0; i < PT; ++i) {
            int c = tid * PT + i;
            if (c < CC) {
                tile_start[c] = run;
                cursor[c] = run << 6;          // padded row slot
                for (int j = 0; j < tcnt[i]; ++j)
                    tile_meta[run + j] = (c << 5) | j;
            }
            run += tcnt[i];
        }
    }
    grid.sync();

    // ---- Phase C: scatter ----
    for (int n = gtid; n < NN; n += COOP_THREADS) {
        int c = labels[n];
        int p = atomicAdd(&cursor[c], 1);
        sorted_idx[p] = n;
    }
}

// ---------------- heavy kernel: r20 (best): pinned B, load-all-first stage ----------------
// Grid = NTILES_MAX x 512 (8 waves). Block t (padded 64-row tile, one class):
// wave w covers 32 cols (w<4: inputs -> max/min/sum; w>=4: inputs2 -> sum).
// B fragments pinned resident via asm "+v" (r19-proven). Stage: ALL 8 float4 loaded
// into R[8] first (one vmcnt window), then cvt+ds_write into fragment-order LDS
// (frag (ma,kc)=1KB; chunk c: row 16ma+((c&15)^kc), kslice c>>4; lane l reads l^kc;
// 0-conflict read, r12-proven). Pads clamp to row 0; fold guards by vrows.
// ~115 regs <= 128 at (512,4) -> 2 blocks/CU, no spill.
__global__ __launch_bounds__(512, 4) void mm_kernel(
    const float* __restrict__ features, const unsigned short* __restrict__ inb,
    const int* __restrict__ sorted_idx, const int* __restrict__ tile_meta,
    const int* __restrict__ counts, const int* __restrict__ ntiles_total,
    float* __restrict__ part_max, float* __restrict__ part_min,
    float* __restrict__ part_sA, float* __restrict__ part_sB)
{
    const int t = blockIdx.x;
    if (t >= *ntiles_total) return;
    const int tid = threadIdx.x;
    const int w   = tid >> 6;
    const int l   = tid & 63;
    const int meta = tile_meta[t];
    const int base_local = (meta & 31) << 6;
    const int cnt  = counts[meta >> 5];
    const int vrows = cnt - base_local;          // valid rows in this tile (>=1)

    __shared__ __align__(16) char ldsA[32768];   // A tile, bf16 fragment order

    // (1) issue B-fragment loads (independent; fill MLP under the idx->row chain)
    bf16x8 bfr[16];
    #pragma unroll
    for (int kc = 0; kc < 8; ++kc)
        #pragma unroll
        for (int nb = 0; nb < 2; ++nb)
            bfr[kc * 2 + nb] = *(const bf16x8*)(inb + (((size_t)((2 * w + nb) * 8 + kc) * 64 + l) << 3));

    // (2) stage: ALL row loads first (one latency window), then cvt+ds_write
    {
        const int m0 = tid >> 3;
        const int g  = tid & 7;
        int idx = t * 64 + ((m0 < vrows) ? m0 : 0);   // clamp pads to tile row 0
        int n   = sorted_idx[idx];
        const float* src = features + (size_t)n * DD + g * 8;
        float4 R[8];
        #pragma unroll
        for (int s = 0; s < 4; ++s) {
            R[2 * s]     = *(const float4*)(src + s * 64);
            R[2 * s + 1] = *(const float4*)(src + s * 64 + 4);
        }
        const int ma = m0 >> 4;
        #pragma unroll
        for (int s = 0; s < 4; ++s) {
            u16x8 o = cvt8u(R[2 * s], R[2 * s + 1]);
            int crow = s * 8 + g;            // bf16 16B-chunk index within row, 0..31
            int kc   = crow >> 2;
            int ks   = crow & 3;
            int cch  = (ks << 4) | ((m0 & 15) ^ kc);
            *(u16x8*)(&ldsA[0] + (((ma * 8 + kc) << 10) | (cch << 4))) = o;
        }
    }

    // (3) pin B fragments resident (cannot be sunk/rematerialized past here)
    #pragma unroll
    for (int i = 0; i < 16; ++i)
        asm volatile("" : "+v"(bfr[i]));

    __syncthreads();

    // (4) MFMA: pure LDS + MFMA. acc[ma][nb], ma=4 row-frags, nb=2 col-frags.
    f32x4 acc[4][2];
    #pragma unroll
    for (int ma = 0; ma < 4; ++ma)
        #pragma unroll
        for (int nb = 0; nb < 2; ++nb)
            acc[ma][nb] = (f32x4){0.f, 0.f, 0.f, 0.f};

    #pragma unroll
    for (int kc = 0; kc < 8; ++kc) {
        int lx = (l ^ kc) << 4;
        #pragma unroll
        for (int ma = 0; ma < 4; ++ma) {
            bf16x8 a = *(const bf16x8*)(&ldsA[0] + ((ma * 8 + kc) << 10) + lx);
            acc[ma][0] = __builtin_amdgcn_mfma_f32_16x16x32_bf16(a, bfr[kc * 2 + 0], acc[ma][0], 0, 0, 0);
            acc[ma][1] = __builtin_amdgcn_mfma_f32_16x16x32_bf16(a, bfr[kc * 2 + 1], acc[ma][1], 0, 0, 0);
        }
    }

    // fold (guard by row validity: pad rows hold row-0 duplicates)
    const int h4 = (l >> 4) << 2;
    const bool do_mm = (w < 4);
    float sm[2] = {0.f, 0.f};
    float mx[2] = {-3.4e38f, -3.4e38f};
    float mn[2] = { 3.4e38f,  3.4e38f};
    #pragma unroll
    for (int ma = 0; ma < 4; ++ma) {
        #pragma unroll
        for (int reg = 0; reg < 4; ++reg) {
            bool valid = (16 * ma + h4 + reg) < vrows;
            if (valid) {
                #pragma unroll
                for (int nb = 0; nb < 2; ++nb) {
                    float v = acc[ma][nb][reg];
                    sm[nb] += v;
                    if (do_mm) {
                        mx[nb] = fmaxf(mx[nb], v);
                        mn[nb] = fminf(mn[nb], v);
                    }
                }
            }
        }
    }
    #pragma unroll
    for (int nb = 0; nb < 2; ++nb) {
        sm[nb] += __shfl_xor(sm[nb], 16);
        sm[nb] += __shfl_xor(sm[nb], 32);
        if (do_mm) {
            mx[nb] = fmaxf(mx[nb], __shfl_xor(mx[nb], 16));
            mx[nb] = fmaxf(mx[nb], __shfl_xor(mx[nb], 32));
            mn[nb] = fminf(mn[nb], __shfl_xor(mn[nb], 16));
            mn[nb] = fminf(mn[nb], __shfl_xor(mn[nb], 32));
        }
    }
    if (l < 16) {
        #pragma unroll
        for (int nb = 0; nb < 2; ++nb) {
            int col = 32 * (w & 3) + 16 * nb + l;   // 0..127 within its set
            size_t p = (size_t)t * 128 + col;
            if (do_mm) { part_max[p] = mx[nb]; part_min[p] = mn[nb]; part_sA[p] = sm[nb]; }
            else       { part_sB[p] = sm[nb]; }
        }
    }
}

// ---------------- finalize: fold partials + both losses (combine fused) ----------------

__device__ __forceinline__ float blk_reduce_sum(float v) {
    __shared__ float sh[4];
    int lane = threadIdx.x & 63, w = threadIdx.x >> 6;
    #pragma unroll
    for (int o = 32; o; o >>= 1) v += __shfl_down(v, o, 64);
    __syncthreads();
    if (lane == 0) sh[w] = v;
    __syncthreads();
    return sh[0] + sh[1] + sh[2] + sh[3];
}

__device__ __forceinline__ float blk_reduce_max(float v) {
    __shared__ float sh[4];
    int lane = threadIdx.x & 63, w = threadIdx.x >> 6;
    #pragma unroll
    for (int o = 32; o; o >>= 1) v = fmaxf(v, __shfl_down(v, o, 64));
    __syncthreads();
    if (lane == 0) sh[w] = v;
    __syncthreads();
    return fmaxf(fmaxf(sh[0], sh[1]), fmaxf(sh[2], sh[3]));
}

__global__ __launch_bounds__(256) void finalize_kernel(
    const float* __restrict__ part_max, const float* __restrict__ part_min,
    const float* __restrict__ part_sA, const float* __restrict__ part_sB,
    const int* __restrict__ tile_start, const int* __restrict__ counts,
    const int* __restrict__ labels, const int* __restrict__ indexes,
    float* __restrict__ out)
{
    const int b   = blockIdx.x;
    const int tid = threadIdx.x;
    const int tgt = labels[indexes[b]];

    __shared__ float a1[SS], a2[SS];
    __shared__ float sh_etgt;

    float local = 0.f;
    for (int c = tid; c < CC; c += 256) {
        int cnt = counts[c];
        if (cnt > 0) {
            int t0 = tile_start[c];
            int nt = (cnt + 63) >> 6;
            bool src = (c < SS);
            float mx = -3.4e38f, sA = 0.f, sB = 0.f;
            for (int j = 0; j < nt; ++j) {
                size_t p = (size_t)(t0 + j) * 128 + b;
                mx = fmaxf(mx, part_max[p]);
                if (src) { sA += part_sA[p]; sB += part_sB[p]; }
            }
            float v = mx;
            if (c == tgt) {
                float mn = 3.4e38f;
                for (int j = 0; j < nt; ++j)
                    mn = fminf(mn, part_min[(size_t)(t0 + j) * 128 + b]);
                v = mn;
            }
            float e = expf(v * INVTEMP);
            local += e;
            if (c == tgt) sh_etgt = e;
            if (src) {
                float icnt = INVTEMP / (float)cnt;
                a1[c] = sA * icnt;
                a2[c] = sB * icnt;
            }
        } else if (c < SS) {
            a1[c] = 0.f;
            a2[c] = 0.f;
        }
    }
    float sum_e = blk_reduce_sum(local);   // barriers inside -> sh_etgt, a1, a2 visible
    float etgt = sh_etgt;
    float loss_con_b = -logf(etgt / (sum_e + EPSV) + EPSV);

    float m1 = -3.4e38f, m2 = -3.4e38f;
    for (int c = tid; c < SS; c += 256) { m1 = fmaxf(m1, a1[c]); m2 = fmaxf(m2, a2[c]); }
    m1 = blk_reduce_max(m1);
    m2 = blk_reduce_max(m2);
    float s1 = 0.f, s2 = 0.f;
    for (int c = tid; c < SS; c += 256) { s1 += expf(a1[c] - m1); s2 += expf(a2[c] - m2); }
    s1 = blk_reduce_sum(s1);
    s2 = blk_reduce_sum(s2);
    float inv1 = 1.f / s1, inv2 = 1.f / s2;
    float dsum = 0.f;
    for (int c = tid; c < SS; c += 256) {
        float d = expf(a1[c] - m1) * inv1 - expf(a2[c] - m2) * inv2;
        dsum += d * d;
    }
    dsum = blk_reduce_sum(dsum);
    if (tid == 0) {
        atomicAdd(&out[0], loss_con_b * (1.0f / (float)BB));
        atomicAdd(&out[1], dsum * (1.0f / (float)SS));
    }
}

// ---------------- launch ----------------

extern "C" void kernel_launch(void* const* d_in, const int* in_sizes, int n_in,
                              void* d_out, int out_size, void* d_ws, size_t ws_size,
                              hipStream_t stream) {
    const float* inputs   = (const float*)d_in[0];
    const float* inputs2  = (const float*)d_in[1];
    const float* features = (const float*)d_in[2];
    const int*   labels   = (const int*)d_in[3];
    const int*   indexes  = (const int*)d_in[4];

    float* out = (float*)d_out;

    // workspace layout (int-element offsets)
    int* wsi = (int*)d_ws;
    int* counts     = wsi;                                  // [0, 2048)
    int* tile_start = wsi + 2048;                           // [2048, 4096)
    int* cursor     = wsi + 4096;                           // [4096, 6144)
    int* ntiles     = wsi + 6144;                           // [6144, 6160)
    unsigned short* inb = (unsigned short*)(wsi + 6160);    // 65536 ushorts -> [6160, 38928)
    int* tile_meta  = wsi + 38928;                          // NTILES_MAX -> pad to 42496
    int* sorted_idx = wsi + 42496;                          // NTILES_MAX*64 = 228032 -> pad to 270592
    float* part_max = (float*)(wsi + 270592);               // NTILES_MAX*128 floats each
    float* part_min = part_max + (size_t)NTILES_MAX * 128;
    float* part_sA  = part_min + (size_t)NTILES_MAX * 128;
    float* part_sB  = part_sA  + (size_t)NTILES_MAX * 128;

    hipMemsetAsync(counts, 0, 2048 * sizeof(int), stream);

    {
        void* args[] = {
            (void*)&labels, (void*)&counts, (void*)&inputs, (void*)&inputs2,
            (void*)&inb, (void*)&tile_start, (void*)&cursor, (void*)&tile_meta,
            (void*)&ntiles, (void*)&out, (void*)&sorted_idx
        };
        hipLaunchCooperativeKernel((const void*)prep_coop, dim3(COOP_BLOCKS), dim3(256),
                                   args, 0, stream);
    }

    mm_kernel<<<NTILES_MAX, 512, 0, stream>>>(features, inb, sorted_idx, tile_meta,
                                              counts, ntiles,
                                              part_max, part_min, part_sA, part_sB);
    finalize_kernel<<<BB, 256, 0, stream>>>(part_max, part_min, part_sA, part_sB,
                                            tile_start, counts, labels, indexes, out);
}

// Round 23
// 90.986 us; speedup vs baseline: 1.6318x; 1.6318x over previous
//
#include <hip/hip_runtime.h>
#include <hip/hip_bf16.h>

// Problem constants
#define BB 128        // batch
#define NN 100000     // memory bank size
#define DD 256        // feat dim (K)
#define CC 2000       // num classes
#define SS 751        // source classes
#define INVTEMP 20.0f // 1/0.05
#define EPSV 1e-6f

#define HIST_BLOCKS 391    // ceil(100000/256)
#define PREP_BLOCKS 32     // 8192/256 (inputs + inputs2 fragments)
#define NTILES_MAX 3563    // 2000 + 100000/64 upper bound on padded tiles

typedef __attribute__((ext_vector_type(8))) short bf16x8;
typedef __attribute__((ext_vector_type(8))) unsigned short u16x8;
typedef __attribute__((ext_vector_type(4))) float f32x4;

__device__ __forceinline__ unsigned short f2bf(float x) {
    unsigned int u = __float_as_uint(x);
    u += 0x7fffu + ((u >> 16) & 1u);   // round-to-nearest-even
    return (unsigned short)(u >> 16);
}

// 8x f32 -> 8x bf16 (16B) via HW packed converts (RNE)
__device__ __forceinline__ u16x8 cvt8u(float4 a, float4 b) {
    union { unsigned u[4]; u16x8 v; } cv;
    asm("v_cvt_pk_bf16_f32 %0, %1, %2" : "=v"(cv.u[0]) : "v"(a.x), "v"(a.y));
    asm("v_cvt_pk_bf16_f32 %0, %1, %2" : "=v"(cv.u[1]) : "v"(a.z), "v"(a.w));
    asm("v_cvt_pk_bf16_f32 %0, %1, %2" : "=v"(cv.u[2]) : "v"(b.x), "v"(b.y));
    asm("v_cvt_pk_bf16_f32 %0, %1, %2" : "=v"(cv.u[3]) : "v"(b.z), "v"(b.w));
    return cv.v;
}

// ---------------- fused: histogram + input-fragment prep (both input sets) ----------------
// inb: 16B chunk ch = (nr*8 + kc)*64 + l holds row nr*16+(l&15)
// (rows 0..127 inputs, 128..255 inputs2), k = kc*32 + (l>>4)*8 + j.
__global__ __launch_bounds__(256) void hist_prep_kernel(
    const int* __restrict__ labels, int* __restrict__ counts,
    const float* __restrict__ in1, const float* __restrict__ in2,
    unsigned short* __restrict__ inb)
{
    int bid = blockIdx.x;
    if (bid < HIST_BLOCKS) {
        int n = bid * 256 + threadIdx.x;
        if (n < NN) atomicAdd(&counts[labels[n]], 1);
    } else {
        int ch = (bid - HIST_BLOCKS) * 256 + threadIdx.x;  // 0..8191
        if (ch >= 8192) return;
        int l  = ch & 63;
        int kc = (ch >> 6) & 7;
        int nr = ch >> 9;
        int row = nr * 16 + (l & 15);
        const float* src = (row < BB) ? (in1 + (size_t)row * DD)
                                      : (in2 + (size_t)(row - BB) * DD);
        int k0 = kc * 32 + ((l >> 4) << 3);
        u16x8 o;
        #pragma unroll
        for (int j = 0; j < 8; ++j) o[j] = f2bf(src[k0 + j]);
        *(u16x8*)(inb + (size_t)ch * 8) = o;
    }
}

// ---------------- scan: padded (64-aligned) tile geometry + per-tile metadata ----------------
__global__ __launch_bounds__(256) void scan_kernel(const int* __restrict__ counts,
                                                   int* __restrict__ tile_start,
                                                   int* __restrict__ cursor,
                                                   int* __restrict__ tile_meta,
                                                   int* __restrict__ ntiles_total,
                                                   float* __restrict__ out) {
    const int PT = 8;
    int tid = threadIdx.x;
    if (tid == 0) { out[0] = 0.f; out[1] = 0.f; }
    int tcnt[PT];
    int tot = 0;
    #pragma unroll
    for (int i = 0; i < PT; ++i) {
        int c = tid * PT + i;
        tcnt[i] = (c < CC) ? ((counts[c] + 63) >> 6) : 0;
        tot += tcnt[i];
    }
    __shared__ int sh[256];
    sh[tid] = tot;
    __syncthreads();
    for (int ofs = 1; ofs < 256; ofs <<= 1) {
        int v = (tid >= ofs) ? sh[tid - ofs] : 0;
        __syncthreads();
        sh[tid] += v;
        __syncthreads();
    }
    if (tid == 255) *ntiles_total = sh[255];
    int run = sh[tid] - tot;
    #pragma unroll
    for (int i = 0; i < PT; ++i) {
        int c = tid * PT + i;
        if (c < CC) {
            tile_start[c] = run;
            cursor[c] = run << 6;          // padded row slot
            for (int j = 0; j < tcnt[i]; ++j)
                tile_meta[run + j] = (c << 5) | j;
        }
        run += tcnt[i];
    }
}

// ---------------- scatter: padded class-sorted INDEX list only (no data copy) ----------------
__global__ void scatter_idx(const int* __restrict__ labels, int* __restrict__ cursor,
                            int* __restrict__ sorted_idx) {
    int n = blockIdx.x * 256 + threadIdx.x;
    if (n < NN) {
        int c = labels[n];
        int p = atomicAdd(&cursor[c], 1);
        sorted_idx[p] = n;
    }
}

// ---------------- heavy kernel: pinned B fragments, load-all-first stage ----------------
// Grid = NTILES_MAX x 512 (8 waves). Block t (padded 64-row tile, one class):
// wave w covers 32 cols (w<4: inputs -> max/min/sum; w>=4: inputs2 -> sum).
// B fragments pinned resident via asm "+v" (r19-proven: compiler cannot sink the
// loads past the pin). Stage loads ALL 8 float4 into R[8] first (one vmcnt window,
// 8 loads in flight), then cvt+ds_write into fragment-order LDS (frag (ma,kc)=1KB;
// chunk c: row 16ma+((c&15)^kc), kslice c>>4; lane l reads chunk l^kc; 0-conflict
// read, r12-proven). Pads clamp to row 0; fold guards by vrows.
// ~115 regs <= 128 at (512,4) -> 2 blocks/CU, no spill.
__global__ __launch_bounds__(512, 4) void mm_kernel(
    const float* __restrict__ features, const unsigned short* __restrict__ inb,
    const int* __restrict__ sorted_idx, const int* __restrict__ tile_meta,
    const int* __restrict__ counts, const int* __restrict__ ntiles_total,
    float* __restrict__ part_max, float* __restrict__ part_min,
    float* __restrict__ part_sA, float* __restrict__ part_sB)
{
    const int t = blockIdx.x;
    if (t >= *ntiles_total) return;
    const int tid = threadIdx.x;
    const int w   = tid >> 6;
    const int l   = tid & 63;
    const int meta = tile_meta[t];
    const int base_local = (meta & 31) << 6;
    const int cnt  = counts[meta >> 5];
    const int vrows = cnt - base_local;          // valid rows in this tile (>=1)

    __shared__ __align__(16) char ldsA[32768];   // A tile, bf16 fragment order

    // (1) issue B-fragment loads (independent; fill MLP under the idx->row chain)
    bf16x8 bfr[16];
    #pragma unroll
    for (int kc = 0; kc < 8; ++kc)
        #pragma unroll
        for (int nb = 0; nb < 2; ++nb)
            bfr[kc * 2 + nb] = *(const bf16x8*)(inb + (((size_t)((2 * w + nb) * 8 + kc) * 64 + l) << 3));

    // (2) stage: ALL row loads first (one latency window), then cvt+ds_write
    {
        const int m0 = tid >> 3;
        const int g  = tid & 7;
        int idx = t * 64 + ((m0 < vrows) ? m0 : 0);   // clamp pads to tile row 0
        int n   = sorted_idx[idx];
        const float* src = features + (size_t)n * DD + g * 8;
        float4 R[8];
        #pragma unroll
        for (int s = 0; s < 4; ++s) {
            R[2 * s]     = *(const float4*)(src + s * 64);
            R[2 * s + 1] = *(const float4*)(src + s * 64 + 4);
        }
        const int ma = m0 >> 4;
        #pragma unroll
        for (int s = 0; s < 4; ++s) {
            u16x8 o = cvt8u(R[2 * s], R[2 * s + 1]);
            int crow = s * 8 + g;            // bf16 16B-chunk index within row, 0..31
            int kc   = crow >> 2;
            int ks   = crow & 3;
            int cch  = (ks << 4) | ((m0 & 15) ^ kc);
            *(u16x8*)(&ldsA[0] + (((ma * 8 + kc) << 10) | (cch << 4))) = o;
        }
    }

    // (3) pin B fragments resident (cannot be sunk/rematerialized past here)
    #pragma unroll
    for (int i = 0; i < 16; ++i)
        asm volatile("" : "+v"(bfr[i]));

    __syncthreads();

    // (4) MFMA: pure LDS + MFMA. acc[ma][nb], ma=4 row-frags, nb=2 col-frags.
    f32x4 acc[4][2];
    #pragma unroll
    for (int ma = 0; ma < 4; ++ma)
        #pragma unroll
        for (int nb = 0; nb < 2; ++nb)
            acc[ma][nb] = (f32x4){0.f, 0.f, 0.f, 0.f};

    #pragma unroll
    for (int kc = 0; kc < 8; ++kc) {
        int lx = (l ^ kc) << 4;
        #pragma unroll
        for (int ma = 0; ma < 4; ++ma) {
            bf16x8 a = *(const bf16x8*)(&ldsA[0] + ((ma * 8 + kc) << 10) + lx);
            acc[ma][0] = __builtin_amdgcn_mfma_f32_16x16x32_bf16(a, bfr[kc * 2 + 0], acc[ma][0], 0, 0, 0);
            acc[ma][1] = __builtin_amdgcn_mfma_f32_16x16x32_bf16(a, bfr[kc * 2 + 1], acc[ma][1], 0, 0, 0);
        }
    }

    // fold (guard by row validity: pad rows hold row-0 duplicates)
    const int h4 = (l >> 4) << 2;
    const bool do_mm = (w < 4);
    float sm[2] = {0.f, 0.f};
    float mx[2] = {-3.4e38f, -3.4e38f};
    float mn[2] = { 3.4e38f,  3.4e38f};
    #pragma unroll
    for (int ma = 0; ma < 4; ++ma) {
        #pragma unroll
        for (int reg = 0; reg < 4; ++reg) {
            bool valid = (16 * ma + h4 + reg) < vrows;
            if (valid) {
                #pragma unroll
                for (int nb = 0; nb < 2; ++nb) {
                    float v = acc[ma][nb][reg];
                    sm[nb] += v;
                    if (do_mm) {
                        mx[nb] = fmaxf(mx[nb], v);
                        mn[nb] = fminf(mn[nb], v);
                    }
                }
            }
        }
    }
    #pragma unroll
    for (int nb = 0; nb < 2; ++nb) {
        sm[nb] += __shfl_xor(sm[nb], 16);
        sm[nb] += __shfl_xor(sm[nb], 32);
        if (do_mm) {
            mx[nb] = fmaxf(mx[nb], __shfl_xor(mx[nb], 16));
            mx[nb] = fmaxf(mx[nb], __shfl_xor(mx[nb], 32));
            mn[nb] = fminf(mn[nb], __shfl_xor(mn[nb], 16));
            mn[nb] = fminf(mn[nb], __shfl_xor(mn[nb], 32));
        }
    }
    if (l < 16) {
        #pragma unroll
        for (int nb = 0; nb < 2; ++nb) {
            int col = 32 * (w & 3) + 16 * nb + l;   // 0..127 within its set
            size_t p = (size_t)t * 128 + col;
            if (do_mm) { part_max[p] = mx[nb]; part_min[p] = mn[nb]; part_sA[p] = sm[nb]; }
            else       { part_sB[p] = sm[nb]; }
        }
    }
}

// ---------------- finalize: fold partials + both losses (combine fused) ----------------

__device__ __forceinline__ float blk_reduce_sum(float v) {
    __shared__ float sh[4];
    int lane = threadIdx.x & 63, w = threadIdx.x >> 6;
    #pragma unroll
    for (int o = 32; o; o >>= 1) v += __shfl_down(v, o, 64);
    __syncthreads();
    if (lane == 0) sh[w] = v;
    __syncthreads();
    return sh[0] + sh[1] + sh[2] + sh[3];
}

__device__ __forceinline__ float blk_reduce_max(float v) {
    __shared__ float sh[4];
    int lane = threadIdx.x & 63, w = threadIdx.x >> 6;
    #pragma unroll
    for (int o = 32; o; o >>= 1) v = fmaxf(v, __shfl_down(v, o, 64));
    __syncthreads();
    if (lane == 0) sh[w] = v;
    __syncthreads();
    return fmaxf(fmaxf(sh[0], sh[1]), fmaxf(sh[2], sh[3]));
}

__global__ __launch_bounds__(256) void finalize_kernel(
    const float* __restrict__ part_max, const float* __restrict__ part_min,
    const float* __restrict__ part_sA, const float* __restrict__ part_sB,
    const int* __restrict__ tile_start, const int* __restrict__ counts,
    const int* __restrict__ labels, const int* __restrict__ indexes,
    float* __restrict__ out)
{
    const int b   = blockIdx.x;
    const int tid = threadIdx.x;
    const int tgt = labels[indexes[b]];

    __shared__ float a1[SS], a2[SS];
    __shared__ float sh_etgt;

    float local = 0.f;
    for (int c = tid; c < CC; c += 256) {
        int cnt = counts[c];
        if (cnt > 0) {
            int t0 = tile_start[c];
            int nt = (cnt + 63) >> 6;
            bool src = (c < SS);
            float mx = -3.4e38f, sA = 0.f, sB = 0.f;
            for (int j = 0; j < nt; ++j) {
                size_t p = (size_t)(t0 + j) * 128 + b;
                mx = fmaxf(mx, part_max[p]);
                if (src) { sA += part_sA[p]; sB += part_sB[p]; }
            }
            float v = mx;
            if (c == tgt) {
                float mn = 3.4e38f;
                for (int j = 0; j < nt; ++j)
                    mn = fminf(mn, part_min[(size_t)(t0 + j) * 128 + b]);
                v = mn;
            }
            float e = expf(v * INVTEMP);
            local += e;
            if (c == tgt) sh_etgt = e;
            if (src) {
                float icnt = INVTEMP / (float)cnt;
                a1[c] = sA * icnt;
                a2[c] = sB * icnt;
            }
        } else if (c < SS) {
            a1[c] = 0.f;
            a2[c] = 0.f;
        }
    }
    float sum_e = blk_reduce_sum(local);   // barriers inside -> sh_etgt, a1, a2 visible
    float etgt = sh_etgt;
    float loss_con_b = -logf(etgt / (sum_e + EPSV) + EPSV);

    float m1 = -3.4e38f, m2 = -3.4e38f;
    for (int c = tid; c < SS; c += 256) { m1 = fmaxf(m1, a1[c]); m2 = fmaxf(m2, a2[c]); }
    m1 = blk_reduce_max(m1);
    m2 = blk_reduce_max(m2);
    float s1 = 0.f, s2 = 0.f;
    for (int c = tid; c < SS; c += 256) { s1 += expf(a1[c] - m1); s2 += expf(a2[c] - m2); }
    s1 = blk_reduce_sum(s1);
    s2 = blk_reduce_sum(s2);
    float inv1 = 1.f / s1, inv2 = 1.f / s2;
    float dsum = 0.f;
    for (int c = tid; c < SS; c += 256) {
        float d = expf(a1[c] - m1) * inv1 - expf(a2[c] - m2) * inv2;
        dsum += d * d;
    }
    dsum = blk_reduce_sum(dsum);
    if (tid == 0) {
        atomicAdd(&out[0], loss_con_b * (1.0f / (float)BB));
        atomicAdd(&out[1], dsum * (1.0f / (float)SS));
    }
}

// ---------------- launch ----------------

extern "C" void kernel_launch(void* const* d_in, const int* in_sizes, int n_in,
                              void* d_out, int out_size, void* d_ws, size_t ws_size,
                              hipStream_t stream) {
    const float* inputs   = (const float*)d_in[0];
    const float* inputs2  = (const float*)d_in[1];
    const float* features = (const float*)d_in[2];
    const int*   labels   = (const int*)d_in[3];
    const int*   indexes  = (const int*)d_in[4];

    float* out = (float*)d_out;

    // workspace layout (int-element offsets)
    int* wsi = (int*)d_ws;
    int* counts     = wsi;                                  // [0, 2048)
    int* tile_start = wsi + 2048;                           // [2048, 4096)
    int* cursor     = wsi + 4096;                           // [4096, 6144)
    int* ntiles     = wsi + 6144;                           // [6144, 6160)
    unsigned short* inb = (unsigned short*)(wsi + 6160);    // 65536 ushorts -> [6160, 38928)
    int* tile_meta  = wsi + 38928;                          // NTILES_MAX -> pad to 42496
    int* sorted_idx = wsi + 42496;                          // NTILES_MAX*64 = 228032 -> pad to 270592
    float* part_max = (float*)(wsi + 270592);               // NTILES_MAX*128 floats each
    float* part_min = part_max + (size_t)NTILES_MAX * 128;
    float* part_sA  = part_min + (size_t)NTILES_MAX * 128;
    float* part_sB  = part_sA  + (size_t)NTILES_MAX * 128;

    hipMemsetAsync(counts, 0, 2048 * sizeof(int), stream);

    hist_prep_kernel<<<HIST_BLOCKS + PREP_BLOCKS, 256, 0, stream>>>(
        labels, counts, inputs, inputs2, inb);
    scan_kernel<<<1, 256, 0, stream>>>(counts, tile_start, cursor, tile_meta, ntiles, out);
    scatter_idx<<<HIST_BLOCKS, 256, 0, stream>>>(labels, cursor, sorted_idx);
    mm_kernel<<<NTILES_MAX, 512, 0, stream>>>(features, inb, sorted_idx, tile_meta,
                                              counts, ntiles,
                                              part_max, part_min, part_sA, part_sB);
    finalize_kernel<<<BB, 256, 0, stream>>>(part_max, part_min, part_sA, part_sB,
                                            tile_start, counts, labels, indexes, out);
}